// Round 1
// baseline (539.254 us; speedup 1.0000x reference)
//
#include <hip/hip_runtime.h>
#include <hip/hip_bf16.h>
#include <cstdint>

#define ENC_DEPTH 8
#define RAYS_PER_BLOCK 64
#define THREADS 512

typedef __attribute__((ext_vector_type(8))) short bf16x8;
typedef __attribute__((ext_vector_type(4))) float f32x4;

__device__ __forceinline__ unsigned short f2bf(float x) {
    union { float f; unsigned u; } v; v.f = x;
    unsigned r = v.u + 0x7fffu + ((v.u >> 16) & 1u);
    return (unsigned short)(r >> 16);
}
__device__ __forceinline__ float bf2f(unsigned short h) {
    union { unsigned u; float f; } v; v.u = ((unsigned)h) << 16;
    return v.f;
}
__device__ __forceinline__ float clamp01(float x) {
    return fminf(fmaxf(x, 0.0f), 1.0f);
}

// LDS strides (in elements):
//  corners_s: per-ray stride 136 bf16 (272 B)
//  feat_s / w1t_s: per-row stride 136 bf16 (272 B) -> MFMA b128 reads spread
//    over all 8 4-bank groups (conflict-free); 144 (288 B) was a 4-way conflict.
//  h1_s: stride 65 fp32
//
// Sync structure: 2 raw barriers per depth (A2->MFMA, MFMA->next overwrite).
// The write-phase -> A2 dependency is same-wave only (each ray's 8 threads
// stage and consume their own corners), so no barrier there. Raw s_barrier +
// lgkmcnt(0) (never vmcnt) lets the d+1 register prefetch of emb/W1/nodes
// stay in flight across the barriers and hide the random-gather HBM latency
// under A2+MFMA of depth d.
__global__ __launch_bounds__(THREADS, 4) void nbvh_kernel(
    const float* __restrict__ orig, const float* __restrict__ endp,
    const int* __restrict__ hist, const float* __restrict__ nodes_min,
    const float* __restrict__ nodes_extent, const float* __restrict__ emb,
    const float* __restrict__ W1, const float* __restrict__ W2,
    const float* __restrict__ W3, float* __restrict__ out)
{
    __shared__ int hist_s[RAYS_PER_BLOCK * ENC_DEPTH];
    __shared__ float oe_s[RAYS_PER_BLOCK * 6];
    __shared__ __align__(16) unsigned short corners_s[RAYS_PER_BLOCK * 136];
    __shared__ __align__(16) unsigned short feat_s[RAYS_PER_BLOCK * 136];
    __shared__ __align__(16) unsigned short w1t_s[64 * 136];
    __shared__ float h1_s[RAYS_PER_BLOCK * 65];

    const int t = threadIdx.x;
    const int r0 = blockIdx.x * RAYS_PER_BLOCK;
    const int wave = t >> 6;
    const int lane = t & 63;
    const int ray_c = t >> 3, k_c = t & 7;   // corner-staging / A2 role
    const int rl = t >> 2, cg = (t & 3) << 4; // W1-staging role

    // ---- prologue: stage history + orig/end for 64 rays ----
    hist_s[t] = hist[r0 * ENC_DEPTH + t];
    if (t < RAYS_PER_BLOCK * 3) {
        int ray = t / 3, c = t - ray * 3;
        oe_s[ray * 6 + c]     = orig[(r0 + ray) * 3 + c];
        oe_s[ray * 6 + 3 + c] = endp[(r0 + ray) * 3 + c];
    }
    // drain LDS writes (hist_s used below same-wave; oe_s cross-wave at barrier)
    asm volatile("s_waitcnt lgkmcnt(0)" ::: "memory");

    // ---- d=0 prefetch into registers ----
    int node0 = hist_s[ray_c << 3];
    const float4* ep = (const float4*)(emb + ((size_t)node0 << 7) + (k_c << 4));
    float4 pf0 = ep[0], pf1 = ep[1], pf2 = ep[2], pf3 = ep[3];
    const float4* wp = (const float4*)(W1 + (size_t)rl * 64 + cg);
    float4 wf0 = wp[0], wf1 = wp[1], wf2 = wp[2], wf3 = wp[3];
    float nm0 = nodes_min[node0 * 3 + 0];
    float nm1 = nodes_min[node0 * 3 + 1];
    float nm2 = nodes_min[node0 * 3 + 2];
    float ex0 = nodes_extent[node0 * 3 + 0];
    float ex1 = nodes_extent[node0 * 3 + 1];
    float ex2 = nodes_extent[node0 * 3 + 2];

    f32x4 acc0 = {0.f, 0.f, 0.f, 0.f};
    f32x4 acc1 = {0.f, 0.f, 0.f, 0.f};
    const int m0 = (wave >> 1) * 16;   // ray-row base of this wave's C stripe
    const int n0 = (wave & 1) * 32;    // col base (two 16-wide tiles)

    __builtin_amdgcn_s_barrier();
    asm volatile("" ::: "memory");

    float nn0 = 0.f, nn1 = 0.f, nn2 = 0.f, en0 = 0.f, en1 = 0.f, en2 = 0.f;

    for (int d = 0; d < ENC_DEPTH; ++d) {
        // ---- write prefetched corners (transpose to [f*8+k], bf16) ----
        {
            float e[16];
            e[0]=pf0.x; e[1]=pf0.y; e[2]=pf0.z; e[3]=pf0.w;
            e[4]=pf1.x; e[5]=pf1.y; e[6]=pf1.z; e[7]=pf1.w;
            e[8]=pf2.x; e[9]=pf2.y; e[10]=pf2.z; e[11]=pf2.w;
            e[12]=pf3.x; e[13]=pf3.y; e[14]=pf3.z; e[15]=pf3.w;
            unsigned short* cb = corners_s + ray_c * 136 + k_c;
            #pragma unroll
            for (int f = 0; f < 16; ++f) cb[f << 3] = f2bf(e[f]);
        }
        // ---- write prefetched W1 chunk, transposed to N-major bf16 ----
        {
            float a[16];
            a[0]=wf0.x; a[1]=wf0.y; a[2]=wf0.z; a[3]=wf0.w;
            a[4]=wf1.x; a[5]=wf1.y; a[6]=wf1.z; a[7]=wf1.w;
            a[8]=wf2.x; a[9]=wf2.y; a[10]=wf2.z; a[11]=wf2.w;
            a[12]=wf3.x; a[13]=wf3.y; a[14]=wf3.z; a[15]=wf3.w;
            unsigned short* wb = w1t_s + (size_t)cg * 136 + rl;
            #pragma unroll
            for (int i = 0; i < 16; ++i) wb[i * 136] = f2bf(a[i]);
        }
        // ---- issue depth d+1 prefetch: stays in flight across both barriers ----
        if (d < ENC_DEPTH - 1) {
            int node1 = hist_s[(ray_c << 3) + d + 1];
            const float4* ep2 = (const float4*)(emb + ((size_t)node1 << 7) + (k_c << 4));
            pf0 = ep2[0]; pf1 = ep2[1]; pf2 = ep2[2]; pf3 = ep2[3];
            const float4* wp2 = (const float4*)(W1 + (size_t)((d + 1) * 128 + rl) * 64 + cg);
            wf0 = wp2[0]; wf1 = wp2[1]; wf2 = wp2[2]; wf3 = wp2[3];
            nn0 = nodes_min[node1 * 3 + 0];
            nn1 = nodes_min[node1 * 3 + 1];
            nn2 = nodes_min[node1 * 3 + 2];
            en0 = nodes_extent[node1 * 3 + 0];
            en1 = nodes_extent[node1 * 3 + 1];
            en2 = nodes_extent[node1 * 3 + 2];
        }

        // ---- A2: trilinear weights + feat chunk (same-wave corners RAW) ----
        {
            const float* oe = oe_s + ray_c * 6;
            float rx = __builtin_amdgcn_rcpf(ex0);
            float ry = __builtin_amdgcn_rcpf(ex1);
            float rz = __builtin_amdgcn_rcpf(ex2);
            float po0 = clamp01((oe[0] - nm0) * rx);
            float po1 = clamp01((oe[1] - nm1) * ry);
            float po2 = clamp01((oe[2] - nm2) * rz);
            float pe0 = clamp01((oe[3] - nm0) * rx);
            float pe1 = clamp01((oe[4] - nm1) * ry);
            float pe2 = clamp01((oe[5] - nm2) * rz);
            float tt = (float)k_c * (1.0f / 7.0f);
            float x = po0 + (pe0 - po0) * tt;
            float y = po1 + (pe1 - po1) * tt;
            float z = po2 + (pe2 - po2) * tt;
            float ox = 1.f - x, oy = 1.f - y, oz = 1.f - z;
            float w[8];
            w[0] = ox * oy * oz;  w[1] = x * oy * oz;
            w[2] = ox * y * oz;   w[3] = ox * oy * z;
            w[4] = x * oy * z;    w[5] = ox * y * z;
            w[6] = x * y * oz;    w[7] = x * y * z;
            const unsigned short* cbase = corners_s + ray_c * 136;
            bf16x8 f0v, f1v;
            #pragma unroll
            for (int f = 0; f < 16; ++f) {
                bf16x8 cv = *(const bf16x8*)(cbase + (f << 3));
                float acc = 0.f;
                #pragma unroll
                for (int k = 0; k < 8; ++k)
                    acc = fmaf(w[k], bf2f((unsigned short)cv[k]), acc);
                unsigned short h = f2bf(acc);
                if (f < 8) f0v[f] = (short)h; else f1v[f - 8] = (short)h;
            }
            unsigned short* fb = feat_s + ray_c * 136 + (k_c << 4);
            *(bf16x8*)fb = f0v;
            *(bf16x8*)(fb + 8) = f1v;
        }

        asm volatile("s_waitcnt lgkmcnt(0)" ::: "memory");
        __builtin_amdgcn_s_barrier();
        asm volatile("" ::: "memory");

        // ---- MFMA: accumulate this K=128 chunk ----
        {
            int q = lane >> 4, c = lane & 15;
            #pragma unroll
            for (int kk = 0; kk < 4; ++kk) {
                int koff = kk * 32 + q * 8;
                bf16x8 af = *(const bf16x8*)(feat_s + (m0 + c) * 136 + koff);
                bf16x8 b0 = *(const bf16x8*)(w1t_s + (n0 + c) * 136 + koff);
                bf16x8 b1 = *(const bf16x8*)(w1t_s + (n0 + 16 + c) * 136 + koff);
                acc0 = __builtin_amdgcn_mfma_f32_16x16x32_bf16(af, b0, acc0, 0, 0, 0);
                acc1 = __builtin_amdgcn_mfma_f32_16x16x32_bf16(af, b1, acc1, 0, 0, 0);
            }
        }

        asm volatile("s_waitcnt lgkmcnt(0)" ::: "memory");
        __builtin_amdgcn_s_barrier();
        asm volatile("" ::: "memory");

        // rotate nodes_min/extent prefetch
        if (d < ENC_DEPTH - 1) {
            nm0 = nn0; nm1 = nn1; nm2 = nn2;
            ex0 = en0; ex1 = en1; ex2 = en2;
        }
    }

    // ---- h1 = relu(GEMM1) -> LDS (C layout: col=lane&15, row=(lane>>4)*4+r) ----
    {
        int colb = lane & 15, rq = (lane >> 4) << 2;
        #pragma unroll
        for (int r = 0; r < 4; ++r) {
            h1_s[(m0 + rq + r) * 65 + n0 + colb]      = fmaxf(acc0[r], 0.f);
            h1_s[(m0 + rq + r) * 65 + n0 + 16 + colb] = fmaxf(acc1[r], 0.f);
        }
    }
    __syncthreads();

    // ---- GEMM2: h2 = relu(h1 @ W2), fp32 VALU; h2 aliases corners_s ----
    float* h2_s = (float*)corners_s;   // stride 66 fp32, 64*66*4 = 16896 B <= 17408 B
    {
        int ray = t >> 3, jg = (t & 7) << 3;
        float s[8];
        #pragma unroll
        for (int j = 0; j < 8; ++j) s[j] = 0.f;
        const float* hrow = h1_s + ray * 65;
        #pragma unroll 8
        for (int i = 0; i < 64; ++i) {
            float hv = hrow[i];
            const float4* wr = (const float4*)(W2 + (i << 6) + jg);
            float4 wa = wr[0], wb = wr[1];
            s[0] = fmaf(hv, wa.x, s[0]); s[1] = fmaf(hv, wa.y, s[1]);
            s[2] = fmaf(hv, wa.z, s[2]); s[3] = fmaf(hv, wa.w, s[3]);
            s[4] = fmaf(hv, wb.x, s[4]); s[5] = fmaf(hv, wb.y, s[5]);
            s[6] = fmaf(hv, wb.z, s[6]); s[7] = fmaf(hv, wb.w, s[7]);
        }
        float* hb = h2_s + ray * 66 + jg;
        #pragma unroll
        for (int j = 0; j < 8; ++j) hb[j] = fmaxf(s[j], 0.f);
    }
    __syncthreads();

    // ---- GEMM3 + output ----
    if (t < 128) {
        int ray = t >> 1, c = t & 1;
        const float* hrow = h2_s + ray * 66;
        float a = 0.f;
        #pragma unroll 16
        for (int i = 0; i < 64; ++i) a = fmaf(hrow[i], W3[i * 2 + c], a);
        if (c) {
            const float* oe = oe_s + ray * 6;
            float dx = oe[3] - oe[0], dy = oe[4] - oe[1], dz = oe[5] - oe[2];
            a *= sqrtf(dx * dx + dy * dy + dz * dz);
        }
        out[((r0 + ray) << 1) + c] = a;
    }
}

extern "C" void kernel_launch(void* const* d_in, const int* in_sizes, int n_in,
                              void* d_out, int out_size, void* d_ws, size_t ws_size,
                              hipStream_t stream) {
    const float* orig = (const float*)d_in[0];
    const float* endp = (const float*)d_in[1];
    const int*   hist = (const int*)d_in[2];
    const float* nmin = (const float*)d_in[3];
    const float* next = (const float*)d_in[4];
    const float* emb  = (const float*)d_in[5];
    const float* W1   = (const float*)d_in[6];
    const float* W2   = (const float*)d_in[7];
    const float* W3   = (const float*)d_in[8];
    float* out = (float*)d_out;
    const int n_rays = in_sizes[0] / 3;
    dim3 grid(n_rays / RAYS_PER_BLOCK);
    nbvh_kernel<<<grid, THREADS, 0, stream>>>(orig, endp, hist, nmin, next,
                                              emb, W1, W2, W3, out);
}